// Round 3
// baseline (351.138 us; speedup 1.0000x reference)
//
#include <hip/hip_runtime.h>
#include <hip/hip_bf16.h>

#define VOCAB 50000
#define EMB   300
#define FILT  400
#define ATT   200
#define BB    4096
#define NN    30

#define ATTP  208        // att padded to 13 n-tiles
#define KC    416        // padded K for attention GEMM (13 K-steps of 32)

typedef short bf16x8 __attribute__((ext_vector_type(8)));
typedef float f32x4  __attribute__((ext_vector_type(4)));
typedef unsigned short u16x4 __attribute__((ext_vector_type(4)));

static __device__ __forceinline__ unsigned short f2bf(float f) {
    __hip_bfloat16 h = __float2bfloat16(f);
    union { __hip_bfloat16 h; unsigned short u; } c; c.h = h; return c.u;
}
static __device__ __forceinline__ float bf2f(unsigned short u) {
    union { unsigned int u; float f; } c; c.u = ((unsigned int)u) << 16; return c.f;
}
// numerics validated (absmax 3.8e-6)
static __device__ __forceinline__ float fast_tanh(float x) {
    float e = __expf(2.f * x);
    return 1.f - 2.f * __builtin_amdgcn_rcpf(e + 1.f);
}

// async global->LDS DMA, 16 B per lane; lds dest = wave-uniform base + lane*16
static __device__ __forceinline__ void dma16(const unsigned short* g, unsigned short* l) {
    __builtin_amdgcn_global_load_lds(
        (const __attribute__((address_space(1))) unsigned int*)(const void*)g,
        (__attribute__((address_space(3))) unsigned int*)(void*)l,
        16, 0, 0);
}

// ---------------- prep: lane-major fragment tiles ----------------
// Bc2 tile tau=(k*10+es)*25+ft, 512 ushorts; pos = lane*8+j holds
//   B[f=ft*16+(lane&15)][e=es*32+(lane>>4)*8+j]  (zero for e>=300)
// Bv2 tile tau=ks*13+at; pos = lane*8+j holds
//   v[fcol=ks*32+(lane>>4)*8+j][att=at*16+(lane&15)]  (zero-padded)
// -> a wave DMA/ds_read of one tile is a verbatim contiguous 1 KB.
__global__ __launch_bounds__(256) void kP(const float* __restrict__ conv_w,
                                          const float* __restrict__ v,
                                          const float* __restrict__ vb,
                                          const float* __restrict__ q,
                                          unsigned short* __restrict__ Bc2,
                                          unsigned short* __restrict__ Bv2,
                                          float* __restrict__ vbp,
                                          float* __restrict__ qp) {
    int t = blockIdx.x * 256 + threadIdx.x;
    const int NBC = 750 * 512;               // 384,000
    if (t < NBC) {
        int tau = t >> 9, off = t & 511;
        int l = off >> 3, j = off & 7;
        int lm = l & 15, qq = l >> 4;
        int ft = tau % 25, es = (tau / 25) % 10, k = tau / 250;
        int f = ft * 16 + lm;
        int e = es * 32 + qq * 8 + j;
        float val = (e < EMB) ? conv_w[((size_t)f * EMB + e) * 3 + k] : 0.f;
        Bc2[t] = f2bf(val);
    } else {
        int t2 = t - NBC;
        if (t2 < 169 * 512) {                // 86,528
            int tau = t2 >> 9, off = t2 & 511;
            int l = off >> 3, j = off & 7;
            int lm = l & 15, qq = l >> 4;
            int ks = tau / 13, at = tau % 13;
            int att = at * 16 + lm;
            int fcol = ks * 32 + qq * 8 + j;
            float val = (att < ATT && fcol < FILT) ? v[(size_t)fcol * ATT + att] : 0.f;
            Bv2[t2] = f2bf(val);
        }
    }
    if (t < ATTP) {
        vbp[t] = (t < ATT) ? vb[t] : 0.f;
        qp[t]  = (t < ATT) ? q[t] : 0.f;
    }
}

// gather 8 consecutive emb cols (fp32) for one token into aR; zeros when invalid
static __device__ __forceinline__ void gatherA(const float* __restrict__ emb,
                                               int tok, int e, float* aR) {
#pragma unroll
    for (int jj = 0; jj < 8; jj++) aR[jj] = 0.f;
    if (tok >= 0 && e < EMB) {
        if (e <= 292) {
            float4 x = *(const float4*)(emb + (size_t)tok * EMB + e);
            float4 y = *(const float4*)(emb + (size_t)tok * EMB + e + 4);
            aR[0] = x.x; aR[1] = x.y; aR[2] = x.z; aR[3] = x.w;
            aR[4] = y.x; aR[5] = y.y; aR[6] = y.z; aR[7] = y.w;
        } else {
#pragma unroll
            for (int jj = 0; jj < 8; jj++) {
                int ee = e + jj;
                if (ee < EMB) aR[jj] = emb[(size_t)tok * EMB + ee];
            }
        }
    }
}

// ---------------- k1: m97-style pipelined conv GEMM, M=64 for 2 blocks/CU ----------------
// 2048 blocks x 320 thr (5 f-waves, one 64-row group = 2 batches). 30 K-steps of 32
// (10 e-chunks x 3 taps). Schedule identical to the verified M=128 version; geometry
// halved so regs (160/wave) + LDS (56.6 KB) admit TWO blocks per CU -> two independent
// barrier domains overlap each other's DMA/barrier drains.
__global__ __launch_bounds__(320, 3) void k1_conv(
    const int* __restrict__ idx,
    const float* __restrict__ emb,
    const unsigned short* __restrict__ Bc2,
    const float* __restrict__ conv_b,
    unsigned short* __restrict__ Cws)
{
    __shared__ unsigned short As[67 * 40];        // 5,360 B (stride 40 ush, 2-way-free)
    __shared__ unsigned short Bs[2 * 25 * 512];   // 51,200 B
    const int bid = blockIdx.x;
    const int t = threadIdx.x;
    const int lane = t & 63, wave = t >> 6;
    const int lm = lane & 15, qq = lane >> 4;
    const int fw = wave;                          // 5 waves, all stagers, rbase = 0

    // A-gather unit: thread t -> row uj, 8-col segment useg
    const int uj = t >> 2, useg = t & 3;
    const bool uact = (t < 268);                  // 67 rows x 4 segs
    int utok = -1;
    if (uact && uj < 64) {
        int ub = uj >> 5, uj2 = uj & 31;
        if (uj2 >= 1 && uj2 <= 30) utok = idx[(bid * 2 + ub) * NN + (uj2 - 1)];
    }

    // prologue: DMA K-steps 0,1 (each wave stages its 5 f-tiles)
#pragma unroll
    for (int s = 0; s < 2; s++) {
#pragma unroll
        for (int nt = 0; nt < 5; nt++) {
            int gt = (s % 3) * 250 + (s / 3) * 25 + fw * 5 + nt;   // (k*10+es)*25+ft
            dma16(Bc2 + (size_t)gt * 512 + lane * 8,
                  Bs + s * 12800 + (fw * 5 + nt) * 512);
        }
    }
    float aR[8];
    gatherA(emb, utok, useg * 8, aR);             // chunk 0

    f32x4 acc[4][5];
#pragma unroll
    for (int mt = 0; mt < 4; mt++)
#pragma unroll
        for (int nt = 0; nt < 5; nt++)
            acc[mt][nt] = (f32x4){0.f, 0.f, 0.f, 0.f};

    for (int es = 0; es < 10; ++es) {
        // publish A chunk es (aR loaded >= 1 full chunk ago)
        if (uact) {
            union { bf16x8 v; unsigned short u[8]; } cv;
#pragma unroll
            for (int jj = 0; jj < 8; jj++) cv.u[jj] = f2bf(aR[jj]);
            *(bf16x8*)(As + uj * 40 + useg * 8) = cv.v;
        }
        __syncthreads();                           // As visible; also drains pending DMA
        if (es < 9) gatherA(emb, utok, (es + 1) * 32 + useg * 8, aR);

#pragma unroll
        for (int k = 0; k < 3; ++k) {
            const int s = es * 3 + k;
            const unsigned short* bb = Bs + (s & 1) * 12800;
            bf16x8 aF[4];
#pragma unroll
            for (int mt = 0; mt < 4; mt++)
                aF[mt] = *(const bf16x8*)(As + (mt * 16 + lm + k) * 40 + qq * 8);
#pragma unroll
            for (int nt = 0; nt < 5; nt++) {
                bf16x8 bF = *(const bf16x8*)(bb + (fw * 5 + nt) * 512 + lane * 8);
#pragma unroll
                for (int mt = 0; mt < 4; mt++)
                    acc[mt][nt] = __builtin_amdgcn_mfma_f32_16x16x32_bf16(aF[mt], bF, acc[mt][nt], 0, 0, 0);
            }
            __syncthreads();                       // buf[s&1] free; DMA(s+1) already drained
            if (s + 2 < 30) {
                const int s2 = s + 2, es2 = s2 / 3, k2 = s2 - es2 * 3;
#pragma unroll
                for (int nt = 0; nt < 5; nt++) {
                    int gt = (k2 * 10 + es2) * 25 + fw * 5 + nt;
                    dma16(Bc2 + (size_t)gt * 512 + lane * 8,
                          Bs + (s & 1) * 12800 + (fw * 5 + nt) * 512);
                }
            }
        }
    }

    // epilogue: bias + relu -> Cws (bf16)
    const int f0 = fw * 80;
    float cb[5];
#pragma unroll
    for (int nt = 0; nt < 5; nt++) cb[nt] = conv_b[f0 + nt * 16 + lm];
#pragma unroll
    for (int mt = 0; mt < 4; mt++) {
#pragma unroll
        for (int r = 0; r < 4; r++) {
            int lrow = mt * 16 + qq * 4 + r;
            int n = lrow & 31;
            int bglob = bid * 2 + (lrow >> 5);
            if (n < NN) {
#pragma unroll
                for (int nt = 0; nt < 5; nt++) {
                    float vv = fmaxf(acc[mt][nt][r] + cb[nt], 0.f);
                    Cws[((size_t)bglob * NN + n) * FILT + f0 + nt * 16 + lm] = f2bf(vv);
                }
            }
        }
    }
}

// ---------------- k2: pipelined attention-logit GEMM ----------------
// 960 blocks x 256 thr (4 waves x 32 rows), N=208, 13 K-steps of 32.
// B: DMA double-buffer (tiles split round-robin over waves); aF: depth-1 reg prefetch.
// launch_bounds(256,3): cap regs at ~170 (usage ~144) -> 3 waves/SIMD to hide L3 A-load latency.
// Writes logits in [n][b] layout so k3's batch-dim softmax is coalesced.
__global__ __launch_bounds__(256, 3) void k2_att(
    const unsigned short* __restrict__ Cws,
    const unsigned short* __restrict__ Bv2,
    const float* __restrict__ vbp, const float* __restrict__ qp,
    float* __restrict__ a_out)
{
    __shared__ unsigned short Bs[2 * 13 * 512];   // 26,624 B
    const int lane = threadIdx.x & 63;
    const int wave = threadIdx.x >> 6;
    const int lm = lane & 15, qq = lane >> 4;
    const int r0 = blockIdx.x * 128 + wave * 32;

#pragma unroll
    for (int s = 0; s < 2; s++)
#pragma unroll
        for (int nt = 0; nt < 13; nt++)
            if ((nt & 3) == wave)
                dma16(Bv2 + (size_t)(s * 13 + nt) * 512 + lane * 8,
                      Bs + s * 6656 + nt * 512);

    bf16x8 aFc[2], aFn[2];
#pragma unroll
    for (int mt = 0; mt < 2; mt++)    // col overrun >=400 reads next row; B rows there are zero
        aFc[mt] = *(const bf16x8*)(Cws + (size_t)(r0 + mt * 16 + lm) * FILT + 8 * qq);

    f32x4 acc[2][13];
#pragma unroll
    for (int mt = 0; mt < 2; mt++)
#pragma unroll
        for (int nt = 0; nt < 13; nt++) acc[mt][nt] = (f32x4){0.f, 0.f, 0.f, 0.f};

    __syncthreads();                               // drains DMA 0,1

    for (int ks = 0; ks < 13; ++ks) {
        if (ks < 12)
#pragma unroll
            for (int mt = 0; mt < 2; mt++)
                aFn[mt] = *(const bf16x8*)(Cws + (size_t)(r0 + mt * 16 + lm) * FILT + (ks + 1) * 32 + 8 * qq);
        const unsigned short* bb = Bs + (ks & 1) * 6656;
#pragma unroll
        for (int nt = 0; nt < 13; nt++) {
            bf16x8 bF = *(const bf16x8*)(bb + nt * 512 + lane * 8);
#pragma unroll
            for (int mt = 0; mt < 2; mt++)
                acc[mt][nt] = __builtin_amdgcn_mfma_f32_16x16x32_bf16(aFc[mt], bF, acc[mt][nt], 0, 0, 0);
        }
        __syncthreads();
        if (ks + 2 < 13)
#pragma unroll
            for (int nt = 0; nt < 13; nt++)
                if ((nt & 3) == wave)
                    dma16(Bv2 + (size_t)((ks + 2) * 13 + nt) * 512 + lane * 8,
                          Bs + (ks & 1) * 6656 + nt * 512);
#pragma unroll
        for (int mt = 0; mt < 2; mt++) aFc[mt] = aFn[mt];
    }

#pragma unroll
    for (int mt = 0; mt < 2; mt++) {
        float rs[4] = {0.f, 0.f, 0.f, 0.f};
#pragma unroll
        for (int nt = 0; nt < 13; nt++) {
            int att = nt * 16 + lm;
            float vbv = vbp[att], qv = qp[att];
#pragma unroll
            for (int r = 0; r < 4; r++)
                rs[r] += fast_tanh(acc[mt][nt][r] + vbv) * qv;   // padded att: acc=0,q=0 -> 0
        }
#pragma unroll
        for (int off = 1; off < 16; off <<= 1)
#pragma unroll
            for (int r = 0; r < 4; r++) rs[r] += __shfl_xor(rs[r], off, 64);
        if (lm == 0) {
#pragma unroll
            for (int r = 0; r < 4; r++) {
                int rg = r0 + mt * 16 + qq * 4 + r;              // rg = b*30 + n
                a_out[(size_t)(rg % NN) * BB + (rg / NN)] = rs[r];  // [n][b] layout
            }
        }
    }
}

// ---------------- k3: softmax over batch dim, coalesced [n][b] layout, in-place ----------------
__global__ __launch_bounds__(1024) void k3_softmax(float* __restrict__ a,
                                                   const int* __restrict__ idx) {
    int n = blockIdx.x, tid = threadIdx.x;
    float4 v4 = *(const float4*)(a + (size_t)n * BB + tid * 4);
    float m = fmaxf(fmaxf(v4.x, v4.y), fmaxf(v4.z, v4.w));
    __shared__ float red[32];
#pragma unroll
    for (int off = 32; off >= 1; off >>= 1) m = fmaxf(m, __shfl_xor(m, off, 64));
    int wv = tid >> 6;
    if ((tid & 63) == 0) red[wv] = m;
    __syncthreads();
#pragma unroll
    for (int w = 0; w < 16; w++) m = fmaxf(m, red[w]);
    float e0 = expf(v4.x - m), e1 = expf(v4.y - m);
    float e2 = expf(v4.z - m), e3 = expf(v4.w - m);
    float s = e0 + e1 + e2 + e3;
#pragma unroll
    for (int off = 32; off >= 1; off >>= 1) s += __shfl_xor(s, off, 64);
    if ((tid & 63) == 0) red[16 + wv] = s;
    __syncthreads();
    s = 0.f;
#pragma unroll
    for (int w = 0; w < 16; w++) s += red[16 + w];
    float inv = 1.f / s;
    int b0 = tid * 4;
    float4 o;
    o.x = e0 * inv * ((idx[(size_t)(b0 + 0) * NN + n] != 0) ? 1.f : 0.f);
    o.y = e1 * inv * ((idx[(size_t)(b0 + 1) * NN + n] != 0) ? 1.f : 0.f);
    o.z = e2 * inv * ((idx[(size_t)(b0 + 2) * NN + n] != 0) ? 1.f : 0.f);
    o.w = e3 * inv * ((idx[(size_t)(b0 + 3) * NN + n] != 0) ? 1.f : 0.f);
    *(float4*)(a + (size_t)n * BB + b0) = o;
}

// ---------------- k4: weighted pooling, vectorized ----------------
__global__ __launch_bounds__(128) void k4_pool(
    const float* __restrict__ alpha, const unsigned short* __restrict__ C,
    float* __restrict__ out)
{
    int b = blockIdx.x;
    int tid = threadIdx.x;
    __shared__ float al[NN];
    if (tid < NN) al[tid] = alpha[(size_t)tid * BB + b];   // [n][b] layout
    __syncthreads();
    if (tid < 100) {
        int f = tid * 4;
        float s0 = 0.f, s1 = 0.f, s2 = 0.f, s3 = 0.f;
        const unsigned short* Cb = C + (size_t)b * (NN * FILT) + f;
#pragma unroll
        for (int n = 0; n < NN; n++) {
            u16x4 c = *(const u16x4*)(Cb + (size_t)n * FILT);
            float a = al[n];
            s0 = fmaf(a, bf2f(c[0]), s0);
            s1 = fmaf(a, bf2f(c[1]), s1);
            s2 = fmaf(a, bf2f(c[2]), s2);
            s3 = fmaf(a, bf2f(c[3]), s3);
        }
        float4 o; o.x = s0; o.y = s1; o.z = s2; o.w = s3;
        *(float4*)(out + (size_t)b * FILT + f) = o;
    }
}

extern "C" void kernel_launch(void* const* d_in, const int* in_sizes, int n_in,
                              void* d_out, int out_size, void* d_ws, size_t ws_size,
                              hipStream_t stream) {
    const int*   idx    = (const int*)d_in[0];
    const float* emb    = (const float*)d_in[1];
    const float* conv_w = (const float*)d_in[2];
    const float* conv_b = (const float*)d_in[3];
    const float* v      = (const float*)d_in[4];
    const float* vb     = (const float*)d_in[5];
    const float* q      = (const float*)d_in[6];
    float* out = (float*)d_out;

    // workspace (total 99,247,104 B <= 99,287,040 proven floor):
    //   Bv2 | vbp | qp | Bc2 (aliased by a_buf after k1) | Cws (+ slack for k2 row overrun)
    char* ws = (char*)d_ws;
    size_t o = 0;
    unsigned short* Bv2 = (unsigned short*)(ws + o); o += (size_t)169 * 512 * 2;      // 173,056
    float* vbp = (float*)(ws + o);                   o += 1024;
    float* qp  = (float*)(ws + o);                   o += 1024;                        // 175,104
    unsigned short* Bc2 = (unsigned short*)(ws + o);
    float* a_buf = (float*)(ws + o);                 // alias of Bc2 (491,520 <= 768,000; Bc2 dead after k1)
    o += (size_t)750 * 512 * 2;                      // -> 943,104
    unsigned short* Cws = (unsigned short*)(ws + o);

    const int NP = 750 * 512 + 169 * 512;            // 470,528
    kP<<<(NP + 255) / 256, 256, 0, stream>>>(conv_w, v, vb, q, Bc2, Bv2, vbp, qp);
    k1_conv<<<BB / 2, 320, 0, stream>>>(idx, emb, Bc2, conv_b, Cws);
    k2_att<<<(BB * NN) / 128, 256, 0, stream>>>(Cws, Bv2, vbp, qp, a_buf);
    k3_softmax<<<NN, 1024, 0, stream>>>(a_buf, idx);
    k4_pool<<<BB, 128, 0, stream>>>(a_buf, Cws, out);
}

// Round 4
// 268.628 us; speedup vs baseline: 1.3072x; 1.3072x over previous
//
#include <hip/hip_runtime.h>
#include <hip/hip_bf16.h>

#define VOCAB 50000
#define EMB   300
#define FILT  400
#define ATT   200
#define BB    4096
#define NN    30

#define ATTP  208        // att padded to 13 n-tiles
#define KC    416        // padded K for attention GEMM (13 K-steps of 32)

typedef short bf16x8 __attribute__((ext_vector_type(8)));
typedef float f32x4  __attribute__((ext_vector_type(4)));
typedef unsigned short u16x4 __attribute__((ext_vector_type(4)));

static __device__ __forceinline__ unsigned short f2bf(float f) {
    __hip_bfloat16 h = __float2bfloat16(f);
    union { __hip_bfloat16 h; unsigned short u; } c; c.h = h; return c.u;
}
static __device__ __forceinline__ float bf2f(unsigned short u) {
    union { unsigned int u; float f; } c; c.u = ((unsigned int)u) << 16; return c.f;
}
// numerics validated (absmax 3.8e-6)
static __device__ __forceinline__ float fast_tanh(float x) {
    float e = __expf(2.f * x);
    return 1.f - 2.f * __builtin_amdgcn_rcpf(e + 1.f);
}

// async global->LDS DMA, 16 B per lane; lds dest = wave-uniform base + lane*16
static __device__ __forceinline__ void dma16(const unsigned short* g, unsigned short* l) {
    __builtin_amdgcn_global_load_lds(
        (const __attribute__((address_space(1))) unsigned int*)(const void*)g,
        (__attribute__((address_space(3))) unsigned int*)(void*)l,
        16, 0, 0);
}

// compiler fence: no codegen, blocks memory-op reordering across raw barriers
#define CFENCE() asm volatile("" ::: "memory")
// barrier with LDS-op retirement (replaces __syncthreads WITHOUT the vmcnt(0) drain)
static __device__ __forceinline__ void bar_lgkm0() {
    asm volatile("s_waitcnt lgkmcnt(0)" ::: "memory");
    __builtin_amdgcn_s_barrier();
    CFENCE();
}
static __device__ __forceinline__ void bar_plain() {
    CFENCE();
    __builtin_amdgcn_s_barrier();
    CFENCE();
}

// ---------------- prep: lane-major fragment tiles ----------------
// Bc2 tile tau=(k*10+es)*25+ft, 512 ushorts; pos = lane*8+j holds
//   B[f=ft*16+(lane&15)][e=es*32+(lane>>4)*8+j]  (zero for e>=300)
// Bv2 tile tau=ks*13+at; pos = lane*8+j holds
//   v[fcol=ks*32+(lane>>4)*8+j][att=at*16+(lane&15)]  (zero-padded)
// -> a wave DMA/ds_read of one tile is a verbatim contiguous 1 KB.
__global__ __launch_bounds__(256) void kP(const float* __restrict__ conv_w,
                                          const float* __restrict__ v,
                                          const float* __restrict__ vb,
                                          const float* __restrict__ q,
                                          unsigned short* __restrict__ Bc2,
                                          unsigned short* __restrict__ Bv2,
                                          float* __restrict__ vbp,
                                          float* __restrict__ qp) {
    int t = blockIdx.x * 256 + threadIdx.x;
    const int NBC = 750 * 512;               // 384,000
    if (t < NBC) {
        int tau = t >> 9, off = t & 511;
        int l = off >> 3, j = off & 7;
        int lm = l & 15, qq = l >> 4;
        int ft = tau % 25, es = (tau / 25) % 10, k = tau / 250;
        int f = ft * 16 + lm;
        int e = es * 32 + qq * 8 + j;
        float val = (e < EMB) ? conv_w[((size_t)f * EMB + e) * 3 + k] : 0.f;
        Bc2[t] = f2bf(val);
    } else {
        int t2 = t - NBC;
        if (t2 < 169 * 512) {                // 86,528
            int tau = t2 >> 9, off = t2 & 511;
            int l = off >> 3, j = off & 7;
            int lm = l & 15, qq = l >> 4;
            int ks = tau / 13, at = tau % 13;
            int att = at * 16 + lm;
            int fcol = ks * 32 + qq * 8 + j;
            float val = (att < ATT && fcol < FILT) ? v[(size_t)fcol * ATT + att] : 0.f;
            Bv2[t2] = f2bf(val);
        }
    }
    if (t < ATTP) {
        vbp[t] = (t < ATT) ? vb[t] : 0.f;
        qp[t]  = (t < ATT) ? q[t] : 0.f;
    }
}

// gather 16 consecutive emb cols (4 x float4) for one token; zeros when invalid.
// e0 is a multiple of 4; ee<300 => ee<=296 => ee+3 in bounds (EMB=300).
static __device__ __forceinline__ void gather16(const float* __restrict__ emb,
                                                int tok, int e0, float4* aR4) {
#pragma unroll
    for (int c = 0; c < 4; c++) {
        float4 z; z.x = 0.f; z.y = 0.f; z.z = 0.f; z.w = 0.f;
        int ee = e0 + c * 4;
        if (tok >= 0 && ee < EMB)
            z = *(const float4*)(emb + (size_t)tok * EMB + ee);
        aR4[c] = z;
    }
}

// ---------------- k1: conv GEMM with counted-vmcnt pipeline (T4) ----------------
// 1024 blocks x 640 thr, M=128 (4 batches), 30 K-steps of 32 (10 e-chunks x 3 taps).
// Role split: waves 0-4 (wg0) = stagers (B-tile DMA ONLY -> exact per-wave vmcnt
// bookkeeping); waves 5-9 = gatherers (emb gather + A-publish; their loads are
// compiler-tracked, wait lands at publish once per es, covered by 3 K-steps).
// Per K-step: [ds_read aF/bF; 20 MFMA] -> bar_lgkm0 (reads retired; buf[s&1] free)
//  -> stagers: issue DMA(s+2) into buf[s&1]; s_waitcnt vmcnt(5)  (= DMA(s+1) landed,
//     DMA(s+2)'s 5 loads STAY IN FLIGHT - never drain to 0 in the main loop)
//  -> bar_plain (all waves see buf[(s+1)&1] ready).
// Tail (es==9, k>=1): no DMA issue; vmcnt(0) drains the last tiles.
__global__ __launch_bounds__(640, 3) void k1_conv(
    const int* __restrict__ idx,
    const float* __restrict__ emb,
    const unsigned short* __restrict__ Bc2,
    const float* __restrict__ conv_b,
    unsigned short* __restrict__ Cws)
{
    __shared__ unsigned short As[131 * 40];       // 10,480 B (stride 40 ush, 2-way-free)
    __shared__ unsigned short Bs[2 * 25 * 512];   // 51,200 B
    const int bid = blockIdx.x;
    const int t = threadIdx.x;
    const int lane = t & 63, wave = t >> 6;
    const int lm = lane & 15, qq = lane >> 4;
    const int wg = wave / 5, fw = wave % 5;
    const int rbase = wg * 64;
    const bool stager = (wave < 5);

    // gatherer unit: waves 5-9, thread g=t-320 -> row uj = g>>1, 16-col half uh = g&1
    const int g = t - 320;
    const int uj = g >> 1, uh = g & 1;
    const bool gact = (!stager) && (g < 262);     // 131 rows x 2 halves
    int utok = -1;
    if (gact && uj < 128) {
        int ub = uj >> 5, uj2 = uj & 31;
        if (uj2 >= 1 && uj2 <= 30) utok = idx[(bid * 4 + ub) * NN + (uj2 - 1)];
    }

    // prologue: stagers DMA K-steps 0,1; gatherers fetch chunk 0
    float4 aR4[4];
    if (stager) {
#pragma unroll
        for (int s = 0; s < 2; s++) {
#pragma unroll
            for (int nt = 0; nt < 5; nt++) {
                int gt = s * 250 + fw * 5 + nt;    // (k*10+es)*25+ft for es=0,k=s
                dma16(Bc2 + (size_t)gt * 512 + lane * 8,
                      Bs + s * 12800 + (fw * 5 + nt) * 512);
            }
        }
        asm volatile("s_waitcnt vmcnt(5)" ::: "memory");   // DMA(0) landed; DMA(1) in flight
    } else if (gact) {
        gather16(emb, utok, uh * 16, aR4);        // chunk 0
    }

    f32x4 acc[4][5];
#pragma unroll
    for (int mt = 0; mt < 4; mt++)
#pragma unroll
        for (int nt = 0; nt < 5; nt++)
            acc[mt][nt] = (f32x4){0.f, 0.f, 0.f, 0.f};

    for (int es = 0; es < 10; ++es) {
        // publish A chunk es (gatherers; compiler inserts the wait for their loads here)
        if (gact) {
            const float* af = (const float*)aR4;
            union { bf16x8 v; unsigned short u[8]; } cv0, cv1;
#pragma unroll
            for (int jj = 0; jj < 8; jj++) { cv0.u[jj] = f2bf(af[jj]); cv1.u[jj] = f2bf(af[8 + jj]); }
            *(bf16x8*)(As + uj * 40 + uh * 16) = cv0.v;
            *(bf16x8*)(As + uj * 40 + uh * 16 + 8) = cv1.v;
        }
        bar_lgkm0();                               // As(es) visible to all
        if (gact && es < 9)
            gather16(emb, utok, (es + 1) * 32 + uh * 16, aR4);

#pragma unroll
        for (int k = 0; k < 3; ++k) {
            const int s = es * 3 + k;
            const unsigned short* bb = Bs + (s & 1) * 12800;
            bf16x8 aF[4];
#pragma unroll
            for (int mt = 0; mt < 4; mt++)
                aF[mt] = *(const bf16x8*)(As + (rbase + mt * 16 + lm + k) * 40 + qq * 8);
#pragma unroll
            for (int nt = 0; nt < 5; nt++) {
                bf16x8 bF = *(const bf16x8*)(bb + (fw * 5 + nt) * 512 + lane * 8);
#pragma unroll
                for (int mt = 0; mt < 4; mt++)
                    acc[mt][nt] = __builtin_amdgcn_mfma_f32_16x16x32_bf16(aF[mt], bF, acc[mt][nt], 0, 0, 0);
            }
            bar_lgkm0();                           // all waves done reading buf[s&1] (and As if k==2)
            if (stager) {
                if (k == 0 || es < 9) {            // s+2 < 30
                    const int s2 = s + 2, es2 = s2 / 3, k2 = s2 - es2 * 3;
#pragma unroll
                    for (int nt = 0; nt < 5; nt++) {
                        int gt = (k2 * 10 + es2) * 25 + fw * 5 + nt;
                        dma16(Bc2 + (size_t)gt * 512 + lane * 8,
                              Bs + (s & 1) * 12800 + (fw * 5 + nt) * 512);
                    }
                    asm volatile("s_waitcnt vmcnt(5)" ::: "memory");   // DMA(s+1) landed
                } else {
                    asm volatile("s_waitcnt vmcnt(0)" ::: "memory");   // tail drain
                }
            }
            bar_plain();                           // buf[(s+1)&1] ready for everyone
        }
    }

    // epilogue: bias + relu -> Cws (bf16)
    const int f0 = fw * 80;
    float cb[5];
#pragma unroll
    for (int nt = 0; nt < 5; nt++) cb[nt] = conv_b[f0 + nt * 16 + lm];
#pragma unroll
    for (int mt = 0; mt < 4; mt++) {
#pragma unroll
        for (int r = 0; r < 4; r++) {
            int lrow = rbase + mt * 16 + qq * 4 + r;
            int n = lrow & 31;
            int bglob = bid * 4 + (lrow >> 5);
            if (n < NN) {
#pragma unroll
                for (int nt = 0; nt < 5; nt++) {
                    float vv = fmaxf(acc[mt][nt][r] + cb[nt], 0.f);
                    Cws[((size_t)bglob * NN + n) * FILT + f0 + nt * 16 + lm] = f2bf(vv);
                }
            }
        }
    }
}

// ---------------- k2: pipelined attention-logit GEMM ----------------
// 960 blocks x 256 thr (4 waves x 32 rows), N=208, 13 K-steps of 32.
// B: DMA double-buffer (tiles split round-robin over waves); aF: depth-1 reg prefetch.
// Writes logits in [n][b] layout so k3's batch-dim softmax is coalesced.
__global__ __launch_bounds__(256, 3) void k2_att(
    const unsigned short* __restrict__ Cws,
    const unsigned short* __restrict__ Bv2,
    const float* __restrict__ vbp, const float* __restrict__ qp,
    float* __restrict__ a_out)
{
    __shared__ unsigned short Bs[2 * 13 * 512];   // 26,624 B
    const int lane = threadIdx.x & 63;
    const int wave = threadIdx.x >> 6;
    const int lm = lane & 15, qq = lane >> 4;
    const int r0 = blockIdx.x * 128 + wave * 32;

#pragma unroll
    for (int s = 0; s < 2; s++)
#pragma unroll
        for (int nt = 0; nt < 13; nt++)
            if ((nt & 3) == wave)
                dma16(Bv2 + (size_t)(s * 13 + nt) * 512 + lane * 8,
                      Bs + s * 6656 + nt * 512);

    bf16x8 aFc[2], aFn[2];
#pragma unroll
    for (int mt = 0; mt < 2; mt++)    // col overrun >=400 reads next row; B rows there are zero
        aFc[mt] = *(const bf16x8*)(Cws + (size_t)(r0 + mt * 16 + lm) * FILT + 8 * qq);

    f32x4 acc[2][13];
#pragma unroll
    for (int mt = 0; mt < 2; mt++)
#pragma unroll
        for (int nt = 0; nt < 13; nt++) acc[mt][nt] = (f32x4){0.f, 0.f, 0.f, 0.f};

    __syncthreads();                               // drains DMA 0,1

    for (int ks = 0; ks < 13; ++ks) {
        if (ks < 12)
#pragma unroll
            for (int mt = 0; mt < 2; mt++)
                aFn[mt] = *(const bf16x8*)(Cws + (size_t)(r0 + mt * 16 + lm) * FILT + (ks + 1) * 32 + 8 * qq);
        const unsigned short* bb = Bs + (ks & 1) * 6656;
#pragma unroll
        for (int nt = 0; nt < 13; nt++) {
            bf16x8 bF = *(const bf16x8*)(bb + nt * 512 + lane * 8);
#pragma unroll
            for (int mt = 0; mt < 2; mt++)
                acc[mt][nt] = __builtin_amdgcn_mfma_f32_16x16x32_bf16(aFc[mt], bF, acc[mt][nt], 0, 0, 0);
        }
        __syncthreads();
        if (ks + 2 < 13)
#pragma unroll
            for (int nt = 0; nt < 13; nt++)
                if ((nt & 3) == wave)
                    dma16(Bv2 + (size_t)((ks + 2) * 13 + nt) * 512 + lane * 8,
                          Bs + (ks & 1) * 6656 + nt * 512);
#pragma unroll
        for (int mt = 0; mt < 2; mt++) aFc[mt] = aFn[mt];
    }

#pragma unroll
    for (int mt = 0; mt < 2; mt++) {
        float rs[4] = {0.f, 0.f, 0.f, 0.f};
#pragma unroll
        for (int nt = 0; nt < 13; nt++) {
            int att = nt * 16 + lm;
            float vbv = vbp[att], qv = qp[att];
#pragma unroll
            for (int r = 0; r < 4; r++)
                rs[r] += fast_tanh(acc[mt][nt][r] + vbv) * qv;   // padded att: acc=0,q=0 -> 0
        }
#pragma unroll
        for (int off = 1; off < 16; off <<= 1)
#pragma unroll
            for (int r = 0; r < 4; r++) rs[r] += __shfl_xor(rs[r], off, 64);
        if (lm == 0) {
#pragma unroll
            for (int r = 0; r < 4; r++) {
                int rg = r0 + mt * 16 + qq * 4 + r;              // rg = b*30 + n
                a_out[(size_t)(rg % NN) * BB + (rg / NN)] = rs[r];  // [n][b] layout
            }
        }
    }
}

// ---------------- k3: softmax over batch dim, coalesced [n][b] layout, in-place ----------------
__global__ __launch_bounds__(1024) void k3_softmax(float* __restrict__ a,
                                                   const int* __restrict__ idx) {
    int n = blockIdx.x, tid = threadIdx.x;
    float4 v4 = *(const float4*)(a + (size_t)n * BB + tid * 4);
    float m = fmaxf(fmaxf(v4.x, v4.y), fmaxf(v4.z, v4.w));
    __shared__ float red[32];
#pragma unroll
    for (int off = 32; off >= 1; off >>= 1) m = fmaxf(m, __shfl_xor(m, off, 64));
    int wv = tid >> 6;
    if ((tid & 63) == 0) red[wv] = m;
    __syncthreads();
#pragma unroll
    for (int w = 0; w < 16; w++) m = fmaxf(m, red[w]);
    float e0 = expf(v4.x - m), e1 = expf(v4.y - m);
    float e2 = expf(v4.z - m), e3 = expf(v4.w - m);
    float s = e0 + e1 + e2 + e3;
#pragma unroll
    for (int off = 32; off >= 1; off >>= 1) s += __shfl_xor(s, off, 64);
    if ((tid & 63) == 0) red[16 + wv] = s;
    __syncthreads();
    s = 0.f;
#pragma unroll
    for (int w = 0; w < 16; w++) s += red[16 + w];
    float inv = 1.f / s;
    int b0 = tid * 4;
    float4 o;
    o.x = e0 * inv * ((idx[(size_t)(b0 + 0) * NN + n] != 0) ? 1.f : 0.f);
    o.y = e1 * inv * ((idx[(size_t)(b0 + 1) * NN + n] != 0) ? 1.f : 0.f);
    o.z = e2 * inv * ((idx[(size_t)(b0 + 2) * NN + n] != 0) ? 1.f : 0.f);
    o.w = e3 * inv * ((idx[(size_t)(b0 + 3) * NN + n] != 0) ? 1.f : 0.f);
    *(float4*)(a + (size_t)n * BB + b0) = o;
}

// ---------------- k4: weighted pooling, vectorized ----------------
__global__ __launch_bounds__(128) void k4_pool(
    const float* __restrict__ alpha, const unsigned short* __restrict__ C,
    float* __restrict__ out)
{
    int b = blockIdx.x;
    int tid = threadIdx.x;
    __shared__ float al[NN];
    if (tid < NN) al[tid] = alpha[(size_t)tid * BB + b];   // [n][b] layout
    __syncthreads();
    if (tid < 100) {
        int f = tid * 4;
        float s0 = 0.f, s1 = 0.f, s2 = 0.f, s3 = 0.f;
        const unsigned short* Cb = C + (size_t)b * (NN * FILT) + f;
#pragma unroll
        for (int n = 0; n < NN; n++) {
            u16x4 c = *(const u16x4*)(Cb + (size_t)n * FILT);
            float a = al[n];
            s0 = fmaf(a, bf2f(c[0]), s0);
            s1 = fmaf(a, bf2f(c[1]), s1);
            s2 = fmaf(a, bf2f(c[2]), s2);
            s3 = fmaf(a, bf2f(c[3]), s3);
        }
        float4 o; o.x = s0; o.y = s1; o.z = s2; o.w = s3;
        *(float4*)(out + (size_t)b * FILT + f) = o;
    }
}

extern "C" void kernel_launch(void* const* d_in, const int* in_sizes, int n_in,
                              void* d_out, int out_size, void* d_ws, size_t ws_size,
                              hipStream_t stream) {
    const int*   idx    = (const int*)d_in[0];
    const float* emb    = (const float*)d_in[1];
    const float* conv_w = (const float*)d_in[2];
    const float* conv_b = (const float*)d_in[3];
    const float* v      = (const float*)d_in[4];
    const float* vb     = (const float*)d_in[5];
    const float* q      = (const float*)d_in[6];
    float* out = (float*)d_out;

    // workspace (total 99,247,104 B <= 99,287,040 proven floor):
    //   Bv2 | vbp | qp | Bc2 (aliased by a_buf after k1) | Cws (+ slack for k2 row overrun)
    char* ws = (char*)d_ws;
    size_t o = 0;
    unsigned short* Bv2 = (unsigned short*)(ws + o); o += (size_t)169 * 512 * 2;      // 173,056
    float* vbp = (float*)(ws + o);                   o += 1024;
    float* qp  = (float*)(ws + o);                   o += 1024;                        // 175,104
    unsigned short* Bc2 = (unsigned short*)(ws + o);
    float* a_buf = (float*)(ws + o);                 // alias of Bc2 (491,520 <= 768,000; Bc2 dead after k1)
    o += (size_t)750 * 512 * 2;                      // -> 943,104
    unsigned short* Cws = (unsigned short*)(ws + o);

    const int NP = 750 * 512 + 169 * 512;            // 470,528
    kP<<<(NP + 255) / 256, 256, 0, stream>>>(conv_w, v, vb, q, Bc2, Bv2, vbp, qp);
    k1_conv<<<BB / 4, 640, 0, stream>>>(idx, emb, Bc2, conv_b, Cws);
    k2_att<<<(BB * NN) / 128, 256, 0, stream>>>(Cws, Bv2, vbp, qp, a_buf);
    k3_softmax<<<NN, 1024, 0, stream>>>(a_buf, idx);
    k4_pool<<<BB, 128, 0, stream>>>(a_buf, Cws, out);
}